// Round 11
// baseline (165.174 us; speedup 1.0000x reference)
//
#include <hip/hip_runtime.h>

// MemoryAugmentation: value[b,c] = softmax_m(x[b,c] . mem[m]) . mem
// B*C = 8192 rows, H*W = 7744 (= 1936 float4), M = 10 slots.
//
// R11: cross-iteration x-prefetch at 5 waves/SIMD. Evidence so far:
//  - mixing/traffic theories all refuted (R8 stagger, R9 split, R10 dedup)
//  - P2 (write) is at ceiling; P1 (read) runs ~4-5 TB/s vs 6.3 read ceiling
//  - 64-reg tier (R3, 8 waves) can't keep next iter's x loads in flight;
//    128-reg full-batch (R5, 4 waves) traded TLP 1:1 for ILP.
// This round: acc[4][10]=40 + x cur/next 32 + mv immediate (4-8) + addr
// ~= 90 live regs, __launch_bounds__(256,5) caps at 102 -> 5 waves/SIMD,
// x loads get a full iteration (~350cy) of latency slack, mv loads stay
// L2-hot and are hoisted 2-3 deep by the scheduler within the cap.
// P2 is R3's exact verified body (component-wise FMA + nt stores).

#define RROWS   4
#define NM      10
#define NVEC    1936          // 7744 / 4 float4 per row
#define THREADS 256
#define NITER   8             // ceil(1936/256); iters 0..6 full, 7 partial

typedef float f32x4 __attribute__((ext_vector_type(4)));

__global__ __launch_bounds__(THREADS, 5)
void memaug_kernel(const float* __restrict__ x,
                   const float* __restrict__ mem,
                   float* __restrict__ out)
{
    const int tid = threadIdx.x;
    const long r0 = (long)blockIdx.x * RROWS;

    const f32x4* __restrict__ m4 = (const f32x4*)mem;
    const f32x4* __restrict__ xr = (const f32x4*)x + r0 * NVEC;
    f32x4* __restrict__ orow     = (f32x4*)out + r0 * NVEC;

    // ---------------- Phase 1: pipelined scores ----------------
    float acc[RROWS][NM];
#pragma unroll
    for (int j = 0; j < RROWS; ++j)
#pragma unroll
        for (int m = 0; m < NM; ++m) acc[j][m] = 0.f;

    {
        f32x4 xc[RROWS], xn[RROWS];
        int iv = tid;
#pragma unroll
        for (int j = 0; j < RROWS; ++j) xc[j] = xr[j * NVEC + iv];

        for (int it = 0; it < NITER; ++it) {
            const int ivn = iv + THREADS;
            // prefetch next iteration's x tile (full iter of latency slack)
            if (ivn < NVEC) {
#pragma unroll
                for (int j = 0; j < RROWS; ++j) xn[j] = xr[j * NVEC + ivn];
            }
            if (iv < NVEC) {
#pragma unroll
                for (int m = 0; m < NM; ++m) {
                    const f32x4 mv = m4[m * NVEC + iv];
#pragma unroll
                    for (int j = 0; j < RROWS; ++j) {
                        acc[j][m] += xc[j].x * mv.x + xc[j].y * mv.y
                                   + xc[j].z * mv.z + xc[j].w * mv.w;
                    }
                }
            }
#pragma unroll
            for (int j = 0; j < RROWS; ++j) xc[j] = xn[j];
            iv = ivn;
        }
    }

    // ---------------- Wave reduce + softmax (R3 body) ----------------
#pragma unroll
    for (int j = 0; j < RROWS; ++j)
#pragma unroll
        for (int m = 0; m < NM; ++m) {
            float v = acc[j][m];
#pragma unroll
            for (int off = 32; off > 0; off >>= 1)
                v += __shfl_xor(v, off, 64);
            acc[j][m] = v;
        }

    __shared__ float red[4][RROWS][NM];
    __shared__ float prob[RROWS][NM];

    const int wave = tid >> 6;
    const int lane = tid & 63;
    if (lane == 0) {
#pragma unroll
        for (int j = 0; j < RROWS; ++j)
#pragma unroll
            for (int m = 0; m < NM; ++m) red[wave][j][m] = acc[j][m];
    }
    __syncthreads();

    if (tid < RROWS) {
        const int j = tid;
        float s[NM];
        float mx = -1e30f;
#pragma unroll
        for (int m = 0; m < NM; ++m) {
            s[m] = red[0][j][m] + red[1][j][m] + red[2][j][m] + red[3][j][m];
            mx = fmaxf(mx, s[m]);
        }
        float sum = 0.f;
#pragma unroll
        for (int m = 0; m < NM; ++m) { s[m] = expf(s[m] - mx); sum += s[m]; }
        const float inv = 1.f / sum;
#pragma unroll
        for (int m = 0; m < NM; ++m) prob[j][m] = s[m] * inv;
    }
    __syncthreads();

    float p[RROWS][NM];
#pragma unroll
    for (int j = 0; j < RROWS; ++j)
#pragma unroll
        for (int m = 0; m < NM; ++m) p[j][m] = prob[j][m];

    // ---------------- Phase 2: R3's exact verified body ----------------
    for (int iv = tid; iv < NVEC; iv += THREADS) {
        f32x4 mv[NM];
#pragma unroll
        for (int m = 0; m < NM; ++m)
            mv[m] = m4[m * NVEC + iv];

        f32x4 ov[RROWS];
#pragma unroll
        for (int j = 0; j < RROWS; ++j) ov[j] = (f32x4)(0.f);
#pragma unroll
        for (int m = 0; m < NM; ++m) {
#pragma unroll
            for (int j = 0; j < RROWS; ++j) {
                ov[j].x += p[j][m] * mv[m].x;
                ov[j].y += p[j][m] * mv[m].y;
                ov[j].z += p[j][m] * mv[m].z;
                ov[j].w += p[j][m] * mv[m].w;
            }
        }
#pragma unroll
        for (int j = 0; j < RROWS; ++j)
            __builtin_nontemporal_store(ov[j], &orow[j * NVEC + iv]);
    }
}

extern "C" void kernel_launch(void* const* d_in, const int* in_sizes, int n_in,
                              void* d_out, int out_size, void* d_ws, size_t ws_size,
                              hipStream_t stream) {
    const float* x   = (const float*)d_in[0];   // [32,256,88,88] f32
    const float* mem = (const float*)d_in[1];   // [10,88,88] f32
    float* out       = (float*)d_out;           // [32,256,88,88] f32

    const int rows   = 32 * 256;                // 8192
    const int blocks = rows / RROWS;            // 2048

    memaug_kernel<<<blocks, THREADS, 0, stream>>>(x, mem, out);
}